// Round 1
// baseline (2885.140 us; speedup 1.0000x reference)
//
#include <hip/hip_runtime.h>
#include <hip/hip_bf16.h>

#define N_NODES 100000
#define N_EDGES 1600000
#define D 128

// ---------------------------------------------------------------------------
// Kernel 1: support = X @ W   [N,128] = [N,128] @ [128,128]  (f32 vector ALU)
// One block (128 threads) per row; x-row staged in LDS; W streamed from L2.
// ---------------------------------------------------------------------------
__global__ void gemm_rows_kernel(const float* __restrict__ x,
                                 const float* __restrict__ w,
                                 float* __restrict__ support) {
    __shared__ float xs[D];
    const int row = blockIdx.x;
    const int tid = threadIdx.x;          // 0..127 = output feature
    xs[tid] = x[row * D + tid];
    __syncthreads();
    float acc = 0.0f;
#pragma unroll 16
    for (int k = 0; k < D; ++k) {
        acc = fmaf(xs[k], w[k * D + tid], acc);
    }
    support[row * D + tid] = acc;
}

// ---------------------------------------------------------------------------
// Kernel 2: out[n][d] = bias[d]   (initialize output with bias exactly once)
// ---------------------------------------------------------------------------
__global__ void init_bias_kernel(const float* __restrict__ bias,
                                 float* __restrict__ out) {
    const long long total = (long long)N_NODES * D;
    long long i = (long long)blockIdx.x * blockDim.x + threadIdx.x;
    const long long stride = (long long)gridDim.x * blockDim.x;
    for (; i < total; i += stride) {
        out[i] = bias[(int)(i & (D - 1))];
    }
}

// ---------------------------------------------------------------------------
// Kernel 3: scatter-add messages.
// 32 lanes per edge, each lane owns 4 features (float4 gather + 4 atomics).
// ---------------------------------------------------------------------------
__global__ void scatter_kernel(const int* __restrict__ dst_idx,
                               const int* __restrict__ src_idx,
                               const float* __restrict__ ew,
                               const float* __restrict__ support,
                               float* __restrict__ out) {
    const long long t = (long long)blockIdx.x * blockDim.x + threadIdx.x;
    const int e = (int)(t >> 5);          // 32 threads per edge
    if (e >= N_EDGES) return;
    const int c = ((int)t & 31) * 4;      // feature offset 0,4,...,124

    const int s = src_idx[e];
    const int d = dst_idx[e];
    const float w = ew[e];

    const float4 v = *reinterpret_cast<const float4*>(&support[(long long)s * D + c]);
    float* o = &out[(long long)d * D + c];
    atomicAdd(o + 0, v.x * w);
    atomicAdd(o + 1, v.y * w);
    atomicAdd(o + 2, v.z * w);
    atomicAdd(o + 3, v.w * w);
}

extern "C" void kernel_launch(void* const* d_in, const int* in_sizes, int n_in,
                              void* d_out, int out_size, void* d_ws, size_t ws_size,
                              hipStream_t stream) {
    const float* x      = (const float*)d_in[0];   // [N_NODES, D]
    const float* weight = (const float*)d_in[1];   // [D, D]
    const float* bias   = (const float*)d_in[2];   // [D]
    const int*   eidx   = (const int*)d_in[3];     // [2, N_EDGES] int32
    const float* ew     = (const float*)d_in[4];   // [N_EDGES]
    float* out = (float*)d_out;                    // [N_NODES, D]

    const int* dst_idx = eidx;                     // edge_index[0]
    const int* src_idx = eidx + N_EDGES;           // edge_index[1]

    float* support = (float*)d_ws;                 // [N_NODES, D] = 51.2 MB

    // 1) support = X @ W
    gemm_rows_kernel<<<N_NODES, D, 0, stream>>>(x, weight, support);

    // 2) out = bias (broadcast)
    init_bias_kernel<<<2048, 256, 0, stream>>>(bias, out);

    // 3) out[dst] += support[src] * ew
    const long long threads = (long long)N_EDGES * 32;
    const int blk = 256;
    const int grid = (int)((threads + blk - 1) / blk);
    scatter_kernel<<<grid, blk, 0, stream>>>(dst_idx, src_idx, ew, support, out);
}

// Round 2
// 578.873 us; speedup vs baseline: 4.9841x; 4.9841x over previous
//
#include <hip/hip_runtime.h>
#include <hip/hip_bf16.h>

#define N_NODES 100000
#define N_EDGES 1600000
#define D 128

#define SCAN_CHUNK 1024
#define NCHUNK ((N_NODES + SCAN_CHUNK - 1) / SCAN_CHUNK)   // 98

// ---------------------------------------------------------------------------
// Kernel 1: support = X @ W. 16 rows per 256-thread block; W cached in LDS
// (64 KB) so it is read from L2 once per block, not once per row.
// ---------------------------------------------------------------------------
__global__ __launch_bounds__(256) void gemm16_kernel(const float* __restrict__ x,
                                                     const float* __restrict__ w,
                                                     float* __restrict__ support) {
    __shared__ float ws[D * D];        // 64 KB
    __shared__ float xs[16][D];        // 8 KB
    const int t = threadIdx.x;

    // stage W (16384 floats = 4096 float4, 16 per thread)
    const float4* w4 = reinterpret_cast<const float4*>(w);
    float4* ws4 = reinterpret_cast<float4*>(ws);
    for (int i = t; i < D * D / 4; i += 256) ws4[i] = w4[i];

    // stage 16 rows of x (2048 floats = 512 float4, 2 per thread)
    const int row0 = blockIdx.x * 16;
    const float4* x4 = reinterpret_cast<const float4*>(x + (size_t)row0 * D);
    float4* xs4 = reinterpret_cast<float4*>(&xs[0][0]);
    for (int i = t; i < 16 * D / 4; i += 256) xs4[i] = x4[i];
    __syncthreads();

    const int rl = t >> 4;             // local row 0..15
    const int c0 = (t & 15) * 8;       // feature group (8 consecutive outputs)
    float acc[8] = {0, 0, 0, 0, 0, 0, 0, 0};
#pragma unroll 8
    for (int k = 0; k < D; ++k) {
        const float xv = xs[rl][k];
        const float4 wa = *reinterpret_cast<const float4*>(&ws[k * D + c0]);
        const float4 wb = *reinterpret_cast<const float4*>(&ws[k * D + c0 + 4]);
        acc[0] = fmaf(xv, wa.x, acc[0]);
        acc[1] = fmaf(xv, wa.y, acc[1]);
        acc[2] = fmaf(xv, wa.z, acc[2]);
        acc[3] = fmaf(xv, wa.w, acc[3]);
        acc[4] = fmaf(xv, wb.x, acc[4]);
        acc[5] = fmaf(xv, wb.y, acc[5]);
        acc[6] = fmaf(xv, wb.z, acc[6]);
        acc[7] = fmaf(xv, wb.w, acc[7]);
    }
    float* o = &support[(size_t)(row0 + rl) * D + c0];
    reinterpret_cast<float4*>(o)[0] = make_float4(acc[0], acc[1], acc[2], acc[3]);
    reinterpret_cast<float4*>(o)[1] = make_float4(acc[4], acc[5], acc[6], acc[7]);
}

// ---------------------------------------------------------------------------
// Counting sort by dst → CSR
// ---------------------------------------------------------------------------
__global__ void zero_counts_kernel(int* __restrict__ cnt) {
    const int i = blockIdx.x * blockDim.x + threadIdx.x;
    if (i < N_NODES) cnt[i] = 0;
}

__global__ void hist_kernel(const int* __restrict__ dst, int* __restrict__ cnt) {
    for (int e = blockIdx.x * blockDim.x + threadIdx.x; e < N_EDGES;
         e += gridDim.x * blockDim.x)
        atomicAdd(&cnt[dst[e]], 1);
}

// per-chunk totals (chunk = 1024 counts, one 256-thread block each)
__global__ __launch_bounds__(256) void scanA_kernel(const int* __restrict__ cnt,
                                                    int* __restrict__ partial) {
    const int b = blockIdx.x, t = threadIdx.x, base = b * SCAN_CHUNK;
    int s = 0;
    for (int i = t; i < SCAN_CHUNK; i += 256) {
        const int idx = base + i;
        s += (idx < N_NODES) ? cnt[idx] : 0;
    }
    __shared__ int red[4];
#pragma unroll
    for (int o = 32; o >= 1; o >>= 1) s += __shfl_down(s, o);
    if ((t & 63) == 0) red[t >> 6] = s;
    __syncthreads();
    if (t == 0) partial[b] = red[0] + red[1] + red[2] + red[3];
}

// exclusive scan of NCHUNK partials (tiny; single thread)
__global__ void scanB_kernel(int* __restrict__ partial) {
    if (threadIdx.x == 0 && blockIdx.x == 0) {
        int acc = 0;
        for (int i = 0; i < NCHUNK; ++i) {
            const int v = partial[i];
            partial[i] = acc;
            acc += v;
        }
    }
}

// write exclusive offsets (and a second copy used as fill cursors)
__global__ __launch_bounds__(256) void scanC_kernel(const int* __restrict__ cnt,
                                                    const int* __restrict__ partial,
                                                    int* __restrict__ offs,
                                                    int* __restrict__ cursor) {
    __shared__ int tsum[256];
    const int b = blockIdx.x, t = threadIdx.x, base = b * SCAN_CHUNK;
    int loc[4];
    int s = 0;
#pragma unroll
    for (int j = 0; j < 4; ++j) {
        const int idx = base + t * 4 + j;
        loc[j] = (idx < N_NODES) ? cnt[idx] : 0;
        s += loc[j];
    }
    tsum[t] = s;
    __syncthreads();
    // Hillis-Steele inclusive scan over 256 thread sums
    for (int o = 1; o < 256; o <<= 1) {
        const int v = (t >= o) ? tsum[t - o] : 0;
        __syncthreads();
        tsum[t] += v;
        __syncthreads();
    }
    int excl = tsum[t] - s + partial[b];
#pragma unroll
    for (int j = 0; j < 4; ++j) {
        const int idx = base + t * 4 + j;
        if (idx < N_NODES) {
            offs[idx] = excl;
            cursor[idx] = excl;
        }
        excl += loc[j];
    }
    if (b == NCHUNK - 1 && t == 255) offs[N_NODES] = excl;  // = N_EDGES
}

__global__ void fill_kernel(const int* __restrict__ dst, int* __restrict__ cursor,
                            int* __restrict__ sorted_eid) {
    for (int e = blockIdx.x * blockDim.x + threadIdx.x; e < N_EDGES;
         e += gridDim.x * blockDim.x) {
        const int p = atomicAdd(&cursor[dst[e]], 1);
        sorted_eid[p] = e;
    }
}

// ---------------------------------------------------------------------------
// Aggregate: one 64-lane wave per node, lane owns 2 features (float2).
// Register accumulation, single coalesced write, bias folded in.
// ---------------------------------------------------------------------------
__global__ __launch_bounds__(256) void aggregate_kernel(
    const int* __restrict__ offs, const int* __restrict__ sorted_eid,
    const int* __restrict__ src_idx, const float* __restrict__ ew,
    const float* __restrict__ support, const float* __restrict__ bias,
    float* __restrict__ out) {
    const int node = blockIdx.x * (blockDim.x >> 6) + (threadIdx.x >> 6);
    if (node >= N_NODES) return;
    const int lane = threadIdx.x & 63;

    const int beg = offs[node];
    const int end = offs[node + 1];
    float ax = 0.0f, ay = 0.0f;
    for (int i = beg; i < end; ++i) {
        const int e = sorted_eid[i];
        const int s = src_idx[e];
        const float w = ew[e];
        const float2 v =
            *reinterpret_cast<const float2*>(&support[(size_t)s * D + lane * 2]);
        ax = fmaf(w, v.x, ax);
        ay = fmaf(w, v.y, ay);
    }
    const float2 bb = *reinterpret_cast<const float2*>(&bias[lane * 2]);
    *reinterpret_cast<float2*>(&out[(size_t)node * D + lane * 2]) =
        make_float2(ax + bb.x, ay + bb.y);
}

// ---------------------------------------------------------------------------
// Fallback (round-1) kernels, used only if ws_size is too small for CSR.
// ---------------------------------------------------------------------------
__global__ void init_bias_kernel(const float* __restrict__ bias,
                                 float* __restrict__ out) {
    const long long total = (long long)N_NODES * D;
    long long i = (long long)blockIdx.x * blockDim.x + threadIdx.x;
    const long long stride = (long long)gridDim.x * blockDim.x;
    for (; i < total; i += stride) out[i] = bias[(int)(i & (D - 1))];
}

__global__ void scatter_kernel(const int* __restrict__ dst_idx,
                               const int* __restrict__ src_idx,
                               const float* __restrict__ ew,
                               const float* __restrict__ support,
                               float* __restrict__ out) {
    const long long t = (long long)blockIdx.x * blockDim.x + threadIdx.x;
    const int e = (int)(t >> 5);
    if (e >= N_EDGES) return;
    const int c = ((int)t & 31) * 4;
    const int s = src_idx[e];
    const int d = dst_idx[e];
    const float w = ew[e];
    const float4 v = *reinterpret_cast<const float4*>(&support[(long long)s * D + c]);
    float* o = &out[(long long)d * D + c];
    atomicAdd(o + 0, v.x * w);
    atomicAdd(o + 1, v.y * w);
    atomicAdd(o + 2, v.z * w);
    atomicAdd(o + 3, v.w * w);
}

extern "C" void kernel_launch(void* const* d_in, const int* in_sizes, int n_in,
                              void* d_out, int out_size, void* d_ws, size_t ws_size,
                              hipStream_t stream) {
    const float* x      = (const float*)d_in[0];   // [N_NODES, D]
    const float* weight = (const float*)d_in[1];   // [D, D]
    const float* bias   = (const float*)d_in[2];   // [D]
    const int*   eidx   = (const int*)d_in[3];     // [2, N_EDGES] int32
    const float* ew     = (const float*)d_in[4];   // [N_EDGES]
    float* out = (float*)d_out;

    const int* dst_idx = eidx;                     // edge_index[0] (receiver)
    const int* src_idx = eidx + N_EDGES;           // edge_index[1] (neighbor)

    // workspace layout (byte offsets, all 16B-aligned)
    char* ws_base = (char*)d_ws;
    const size_t OFF_SUPPORT = 0;                                   // 51,200,000
    const size_t OFF_COUNTS  = OFF_SUPPORT + (size_t)N_NODES * D * 4;  // 400,000
    const size_t OFF_OFFS    = OFF_COUNTS + 400000;                 // 400,016 (incl pad)
    const size_t OFF_CURSOR  = OFF_OFFS + 400016;                   // 400,000
    const size_t OFF_PARTIAL = OFF_CURSOR + 400000;                 // 400 (pad)
    const size_t OFF_SORTED  = OFF_PARTIAL + 400;                   // 6,400,000
    const size_t NEEDED      = OFF_SORTED + (size_t)N_EDGES * 4;

    float* support   = (float*)(ws_base + OFF_SUPPORT);
    int*   counts    = (int*)(ws_base + OFF_COUNTS);
    int*   offs      = (int*)(ws_base + OFF_OFFS);
    int*   cursor    = (int*)(ws_base + OFF_CURSOR);
    int*   partial   = (int*)(ws_base + OFF_PARTIAL);
    int*   sorted_eid= (int*)(ws_base + OFF_SORTED);

    // 1) support = X @ W   (100000 rows = 6250 blocks x 16 rows)
    gemm16_kernel<<<N_NODES / 16, 256, 0, stream>>>(x, weight, support);

    if (ws_size >= NEEDED) {
        // 2) counting sort by dst → CSR
        zero_counts_kernel<<<(N_NODES + 255) / 256, 256, 0, stream>>>(counts);
        hist_kernel<<<2048, 256, 0, stream>>>(dst_idx, counts);
        scanA_kernel<<<NCHUNK, 256, 0, stream>>>(counts, partial);
        scanB_kernel<<<1, 64, 0, stream>>>(partial);
        scanC_kernel<<<NCHUNK, 256, 0, stream>>>(counts, partial, offs, cursor);
        fill_kernel<<<2048, 256, 0, stream>>>(dst_idx, cursor, sorted_eid);

        // 3) aggregate: one wave per node (4 nodes per 256-thread block)
        aggregate_kernel<<<(N_NODES + 3) / 4, 256, 0, stream>>>(
            offs, sorted_eid, src_idx, ew, support, bias, out);
    } else {
        // fallback: atomic scatter
        init_bias_kernel<<<2048, 256, 0, stream>>>(bias, out);
        const long long threads = (long long)N_EDGES * 32;
        const int grid = (int)((threads + 255) / 256);
        scatter_kernel<<<grid, 256, 0, stream>>>(dst_idx, src_idx, ew, support, out);
    }
}

// Round 3
// 397.266 us; speedup vs baseline: 7.2625x; 1.4571x over previous
//
#include <hip/hip_runtime.h>
#include <hip/hip_bf16.h>

#define N_NODES 100000
#define N_EDGES 1600000
#define D 128

#define SCAN_CHUNK 1024
#define NCHUNK ((N_NODES + SCAN_CHUNK - 1) / SCAN_CHUNK)   // 98

typedef __attribute__((ext_vector_type(8))) short bf16x8;  // 8 bf16 (4 VGPRs)
typedef __attribute__((ext_vector_type(4))) float f32x4;

static __device__ __forceinline__ short f2bf(float f) {
    unsigned u = __builtin_bit_cast(unsigned, f);
    u += 0x7FFFu + ((u >> 16) & 1u);                 // RNE
    return (short)(u >> 16);
}
static __device__ __forceinline__ float bf2f(unsigned short h) {
    unsigned u = ((unsigned)h) << 16;
    return __builtin_bit_cast(float, u);
}

// ---------------------------------------------------------------------------
// Wt[c][k] = bf16(W[k][c])  — 32 KB, built once, L1/L2-resident for the GEMM.
// ---------------------------------------------------------------------------
__global__ void wt_kernel(const float* __restrict__ w, short* __restrict__ wt) {
    const int i = blockIdx.x * blockDim.x + threadIdx.x;
    if (i < D * D) {
        const int k = i / D, c = i % D;
        wt[c * D + k] = f2bf(w[i]);
    }
}

// ---------------------------------------------------------------------------
// support(bf16) = X @ W via MFMA. One wave per 16 rows (6250 waves exactly).
// A: lane holds X[row0 + (l&15)][ks*32 + (l>>4)*8 .. +8] (f32->bf16 in reg).
// B: lane holds Wt[nt*16 + (l&15)][ks*32 + (l>>4)*8 .. +8] (16B contiguous).
// D: col = l&15, row = (l>>4)*4 + q.
// ---------------------------------------------------------------------------
__global__ __launch_bounds__(256) void gemm_mfma_kernel(
    const float* __restrict__ x, const short* __restrict__ wt,
    short* __restrict__ sup) {
    const int wid = blockIdx.x * 4 + (threadIdx.x >> 6);
    if (wid >= N_NODES / 16) return;
    const int l = threadIdx.x & 63;
    const int r = l & 15, g = l >> 4;
    const size_t row0 = (size_t)wid * 16;

    bf16x8 a[4];
    const float* xp = x + (row0 + r) * D + g * 8;
#pragma unroll
    for (int ks = 0; ks < 4; ++ks) {
        const float4 f0 = *reinterpret_cast<const float4*>(xp + ks * 32);
        const float4 f1 = *reinterpret_cast<const float4*>(xp + ks * 32 + 4);
        bf16x8 t;
        t[0] = f2bf(f0.x); t[1] = f2bf(f0.y); t[2] = f2bf(f0.z); t[3] = f2bf(f0.w);
        t[4] = f2bf(f1.x); t[5] = f2bf(f1.y); t[6] = f2bf(f1.z); t[7] = f2bf(f1.w);
        a[ks] = t;
    }

#pragma unroll
    for (int nt = 0; nt < 8; ++nt) {
        f32x4 acc = {0.f, 0.f, 0.f, 0.f};
        const short* wp = wt + (size_t)(nt * 16 + r) * D + g * 8;
#pragma unroll
        for (int ks = 0; ks < 4; ++ks) {
            const bf16x8 b = *reinterpret_cast<const bf16x8*>(wp + ks * 32);
            acc = __builtin_amdgcn_mfma_f32_16x16x32_bf16(a[ks], b, acc, 0, 0, 0);
        }
        short* sp = sup + (row0 + g * 4) * D + nt * 16 + r;
#pragma unroll
        for (int q = 0; q < 4; ++q) sp[q * D] = f2bf(acc[q]);
    }
}

// ---------------------------------------------------------------------------
// Counting sort by dst → CSR with pre-gathered (src, ew) payload.
// ---------------------------------------------------------------------------
__global__ void zero_counts_kernel(int* __restrict__ cnt) {
    const int i = blockIdx.x * blockDim.x + threadIdx.x;
    if (i < N_NODES) cnt[i] = 0;
}

__global__ void hist_kernel(const int* __restrict__ dst, int* __restrict__ cnt) {
    for (int e = blockIdx.x * blockDim.x + threadIdx.x; e < N_EDGES;
         e += gridDim.x * blockDim.x)
        atomicAdd(&cnt[dst[e]], 1);
}

__global__ __launch_bounds__(256) void scanA_kernel(const int* __restrict__ cnt,
                                                    int* __restrict__ partial) {
    const int b = blockIdx.x, t = threadIdx.x, base = b * SCAN_CHUNK;
    int s = 0;
    for (int i = t; i < SCAN_CHUNK; i += 256) {
        const int idx = base + i;
        s += (idx < N_NODES) ? cnt[idx] : 0;
    }
    __shared__ int red[4];
#pragma unroll
    for (int o = 32; o >= 1; o >>= 1) s += __shfl_down(s, o);
    if ((t & 63) == 0) red[t >> 6] = s;
    __syncthreads();
    if (t == 0) partial[b] = red[0] + red[1] + red[2] + red[3];
}

__global__ void scanB_kernel(int* __restrict__ partial) {
    if (threadIdx.x == 0 && blockIdx.x == 0) {
        int acc = 0;
        for (int i = 0; i < NCHUNK; ++i) {
            const int v = partial[i];
            partial[i] = acc;
            acc += v;
        }
    }
}

__global__ __launch_bounds__(256) void scanC_kernel(const int* __restrict__ cnt,
                                                    const int* __restrict__ partial,
                                                    int* __restrict__ offs,
                                                    int* __restrict__ cursor) {
    __shared__ int tsum[256];
    const int b = blockIdx.x, t = threadIdx.x, base = b * SCAN_CHUNK;
    int loc[4];
    int s = 0;
#pragma unroll
    for (int j = 0; j < 4; ++j) {
        const int idx = base + t * 4 + j;
        loc[j] = (idx < N_NODES) ? cnt[idx] : 0;
        s += loc[j];
    }
    tsum[t] = s;
    __syncthreads();
    for (int o = 1; o < 256; o <<= 1) {
        const int v = (t >= o) ? tsum[t - o] : 0;
        __syncthreads();
        tsum[t] += v;
        __syncthreads();
    }
    int excl = tsum[t] - s + partial[b];
#pragma unroll
    for (int j = 0; j < 4; ++j) {
        const int idx = base + t * 4 + j;
        if (idx < N_NODES) {
            offs[idx] = excl;
            cursor[idx] = excl;
        }
        excl += loc[j];
    }
    if (b == NCHUNK - 1 && t == 255) offs[N_NODES] = excl;  // = N_EDGES
}

__global__ void fill_kernel(const int* __restrict__ dst, const int* __restrict__ src,
                            const float* __restrict__ ew, int* __restrict__ cursor,
                            int2* __restrict__ sorted_sw) {
    for (int e = blockIdx.x * blockDim.x + threadIdx.x; e < N_EDGES;
         e += gridDim.x * blockDim.x) {
        const int p = atomicAdd(&cursor[dst[e]], 1);
        sorted_sw[p] = make_int2(src[e], __float_as_int(ew[e]));
    }
}

// ---------------------------------------------------------------------------
// Aggregate: one wave per node; lane owns 2 bf16 features (4B coalesced load).
// Per edge: one wave-uniform 8B payload read + one 256B row gather.
// ---------------------------------------------------------------------------
__global__ __launch_bounds__(256) void aggregate_kernel(
    const int* __restrict__ offs, const int2* __restrict__ sorted_sw,
    const short* __restrict__ sup, const float* __restrict__ bias,
    float* __restrict__ out) {
    const int node = blockIdx.x * 4 + (threadIdx.x >> 6);
    if (node >= N_NODES) return;
    const int lane = threadIdx.x & 63;

    const int beg = offs[node];
    const int end = offs[node + 1];
    float ax = 0.0f, ay = 0.0f;
    for (int i = beg; i < end; ++i) {
        const int2 sw = sorted_sw[i];
        const float w = __int_as_float(sw.y);
        const unsigned v = *reinterpret_cast<const unsigned*>(
            &sup[(size_t)sw.x * D + lane * 2]);
        ax = fmaf(w, bf2f((unsigned short)(v & 0xFFFFu)), ax);
        ay = fmaf(w, bf2f((unsigned short)(v >> 16)), ay);
    }
    const float2 bb = *reinterpret_cast<const float2*>(&bias[lane * 2]);
    *reinterpret_cast<float2*>(&out[(size_t)node * D + lane * 2]) =
        make_float2(ax + bb.x, ay + bb.y);
}

extern "C" void kernel_launch(void* const* d_in, const int* in_sizes, int n_in,
                              void* d_out, int out_size, void* d_ws, size_t ws_size,
                              hipStream_t stream) {
    const float* x      = (const float*)d_in[0];   // [N_NODES, D]
    const float* weight = (const float*)d_in[1];   // [D, D]
    const float* bias   = (const float*)d_in[2];   // [D]
    const int*   eidx   = (const int*)d_in[3];     // [2, N_EDGES] int32
    const float* ew     = (const float*)d_in[4];   // [N_EDGES]
    float* out = (float*)d_out;

    const int* dst_idx = eidx;                     // edge_index[0] (receiver)
    const int* src_idx = eidx + N_EDGES;           // edge_index[1] (neighbor)

    // workspace layout (all sizes multiple of 16 bytes)
    char* p = (char*)d_ws;
    short* sup       = (short*)p;  p += (size_t)N_NODES * D * 2;   // 25,600,000
    int*   counts    = (int*)p;    p += 400000;                    // N_NODES*4
    int*   offs      = (int*)p;    p += 400016;                    // (N_NODES+1)*4 pad
    int*   cursor    = (int*)p;    p += 400000;
    int*   partial   = (int*)p;    p += 416;                       // NCHUNK*4 pad
    short* wt        = (short*)p;  p += (size_t)D * D * 2;         // 32,768
    int2*  sorted_sw = (int2*)p;   p += (size_t)N_EDGES * 8;       // 12,800,000

    // 1) Wt = bf16(W^T), then support(bf16) = X @ W via MFMA
    wt_kernel<<<(D * D + 255) / 256, 256, 0, stream>>>(weight, wt);
    gemm_mfma_kernel<<<(N_NODES / 16 + 3) / 4, 256, 0, stream>>>(x, wt, sup);

    // 2) counting sort by dst → CSR with (src, ew) payload
    zero_counts_kernel<<<(N_NODES + 255) / 256, 256, 0, stream>>>(counts);
    hist_kernel<<<2048, 256, 0, stream>>>(dst_idx, counts);
    scanA_kernel<<<NCHUNK, 256, 0, stream>>>(counts, partial);
    scanB_kernel<<<1, 64, 0, stream>>>(partial);
    scanC_kernel<<<NCHUNK, 256, 0, stream>>>(counts, partial, offs, cursor);
    fill_kernel<<<2048, 256, 0, stream>>>(dst_idx, src_idx, ew, cursor, sorted_sw);

    // 3) aggregate (bias folded in)
    aggregate_kernel<<<(N_NODES + 3) / 4, 256, 0, stream>>>(
        offs, sorted_sw, sup, bias, out);
}

// Round 4
// 313.649 us; speedup vs baseline: 9.1986x; 1.2666x over previous
//
#include <hip/hip_runtime.h>
#include <hip/hip_bf16.h>

#define N_NODES 100000
#define N_EDGES 1600000
#define D 128

#define SCAN_CHUNK 1024
#define NCHUNK ((N_NODES + SCAN_CHUNK - 1) / SCAN_CHUNK)   // 98

typedef __attribute__((ext_vector_type(8))) short bf16x8;  // 8 bf16 (4 VGPRs)
typedef __attribute__((ext_vector_type(4))) float f32x4;

static __device__ __forceinline__ short f2bf(float f) {
    unsigned u = __builtin_bit_cast(unsigned, f);
    u += 0x7FFFu + ((u >> 16) & 1u);                 // RNE
    return (short)(u >> 16);
}
static __device__ __forceinline__ float bf2f(unsigned short h) {
    unsigned u = ((unsigned)h) << 16;
    return __builtin_bit_cast(float, u);
}

// ---------------------------------------------------------------------------
// Wt[c][k] = bf16(W[k][c])  — 32 KB, built once, L2-resident for the GEMM.
// ---------------------------------------------------------------------------
__global__ void wt_kernel(const float* __restrict__ w, short* __restrict__ wt) {
    const int i = blockIdx.x * blockDim.x + threadIdx.x;
    if (i < D * D) {
        const int k = i / D, c = i % D;
        wt[c * D + k] = f2bf(w[i]);
    }
}

// ---------------------------------------------------------------------------
// support(bf16) = X @ W via MFMA. One wave per 16 rows (6250 waves).
// ---------------------------------------------------------------------------
__global__ __launch_bounds__(256) void gemm_mfma_kernel(
    const float* __restrict__ x, const short* __restrict__ wt,
    short* __restrict__ sup) {
    const int wid = blockIdx.x * 4 + (threadIdx.x >> 6);
    if (wid >= N_NODES / 16) return;
    const int l = threadIdx.x & 63;
    const int r = l & 15, g = l >> 4;
    const size_t row0 = (size_t)wid * 16;

    bf16x8 a[4];
    const float* xp = x + (row0 + r) * D + g * 8;
#pragma unroll
    for (int ks = 0; ks < 4; ++ks) {
        const float4 f0 = *reinterpret_cast<const float4*>(xp + ks * 32);
        const float4 f1 = *reinterpret_cast<const float4*>(xp + ks * 32 + 4);
        bf16x8 t;
        t[0] = f2bf(f0.x); t[1] = f2bf(f0.y); t[2] = f2bf(f0.z); t[3] = f2bf(f0.w);
        t[4] = f2bf(f1.x); t[5] = f2bf(f1.y); t[6] = f2bf(f1.z); t[7] = f2bf(f1.w);
        a[ks] = t;
    }

#pragma unroll
    for (int nt = 0; nt < 8; ++nt) {
        f32x4 acc = {0.f, 0.f, 0.f, 0.f};
        const short* wp = wt + (size_t)(nt * 16 + r) * D + g * 8;
#pragma unroll
        for (int ks = 0; ks < 4; ++ks) {
            const bf16x8 b = *reinterpret_cast<const bf16x8*>(wp + ks * 32);
            acc = __builtin_amdgcn_mfma_f32_16x16x32_bf16(a[ks], b, acc, 0, 0, 0);
        }
        short* sp = sup + (row0 + g * 4) * D + nt * 16 + r;
#pragma unroll
        for (int q = 0; q < 4; ++q) sp[q * D] = f2bf(acc[q]);
    }
}

// ---------------------------------------------------------------------------
// Counting sort by dst → CSR with pre-gathered (src, ew) payload.
// ---------------------------------------------------------------------------
__global__ void hist_kernel(const int* __restrict__ dst, int* __restrict__ cnt) {
    for (int e = blockIdx.x * blockDim.x + threadIdx.x; e < N_EDGES;
         e += gridDim.x * blockDim.x)
        atomicAdd(&cnt[dst[e]], 1);
}

__global__ __launch_bounds__(256) void scanA_kernel(const int* __restrict__ cnt,
                                                    int* __restrict__ partial) {
    const int b = blockIdx.x, t = threadIdx.x, base = b * SCAN_CHUNK;
    int s = 0;
    for (int i = t; i < SCAN_CHUNK; i += 256) {
        const int idx = base + i;
        s += (idx < N_NODES) ? cnt[idx] : 0;
    }
    __shared__ int red[4];
#pragma unroll
    for (int o = 32; o >= 1; o >>= 1) s += __shfl_down(s, o);
    if ((t & 63) == 0) red[t >> 6] = s;
    __syncthreads();
    if (t == 0) partial[b] = red[0] + red[1] + red[2] + red[3];
}

// exclusive scan of NCHUNK partials — one 64-lane wave, 2 values per lane.
__global__ void scanB_kernel(int* __restrict__ partial) {
    const int l = threadIdx.x;          // 0..63
    const int i0 = l * 2, i1 = l * 2 + 1;
    const int v0 = (i0 < NCHUNK) ? partial[i0] : 0;
    const int v1 = (i1 < NCHUNK) ? partial[i1] : 0;
    int s = v0 + v1;
#pragma unroll
    for (int o = 1; o < 64; o <<= 1) {
        const int t = __shfl_up(s, o);
        if (l >= o) s += t;
    }
    const int excl = s - (v0 + v1);
    if (i0 < NCHUNK) partial[i0] = excl;
    if (i1 < NCHUNK) partial[i1] = excl + v0;
}

__global__ __launch_bounds__(256) void scanC_kernel(const int* __restrict__ cnt,
                                                    const int* __restrict__ partial,
                                                    int* __restrict__ offs,
                                                    int* __restrict__ cursor) {
    __shared__ int tsum[256];
    const int b = blockIdx.x, t = threadIdx.x, base = b * SCAN_CHUNK;
    int loc[4];
    int s = 0;
#pragma unroll
    for (int j = 0; j < 4; ++j) {
        const int idx = base + t * 4 + j;
        loc[j] = (idx < N_NODES) ? cnt[idx] : 0;
        s += loc[j];
    }
    tsum[t] = s;
    __syncthreads();
    for (int o = 1; o < 256; o <<= 1) {
        const int v = (t >= o) ? tsum[t - o] : 0;
        __syncthreads();
        tsum[t] += v;
        __syncthreads();
    }
    int excl = tsum[t] - s + partial[b];
#pragma unroll
    for (int j = 0; j < 4; ++j) {
        const int idx = base + t * 4 + j;
        if (idx < N_NODES) {
            offs[idx] = excl;
            cursor[idx] = excl;
        }
        excl += loc[j];
    }
    if (b == NCHUNK - 1 && t == 255) offs[N_NODES] = excl;  // = N_EDGES
}

__global__ void fill_kernel(const int* __restrict__ dst, const int* __restrict__ src,
                            const float* __restrict__ ew, int* __restrict__ cursor,
                            int2* __restrict__ sorted_sw) {
    for (int e = blockIdx.x * blockDim.x + threadIdx.x; e < N_EDGES;
         e += gridDim.x * blockDim.x) {
        const int p = atomicAdd(&cursor[dst[e]], 1);
        sorted_sw[p] = make_int2(src[e], __float_as_int(ew[e]));
    }
}

// ---------------------------------------------------------------------------
// Aggregate: one wave per node; 4 edge-groups x 16 lanes; lane loads bf16x8
// (16 B) of the gathered row -> 4 independent row-gathers in flight, trip
// count ~deg/4. Cross-group combine via 2 shfl_xor steps; group 0 writes.
// ---------------------------------------------------------------------------
__global__ __launch_bounds__(256) void aggregate_kernel(
    const int* __restrict__ offs, const int2* __restrict__ sorted_sw,
    const short* __restrict__ sup, const float* __restrict__ bias,
    float* __restrict__ out) {
    const int node = blockIdx.x * 4 + (threadIdx.x >> 6);
    if (node >= N_NODES) return;
    const int lane = threadIdx.x & 63;
    const int g = lane >> 4;            // edge group 0..3
    const int fl = lane & 15;           // feature lane: features fl*8 .. fl*8+7

    const int beg = offs[node];
    const int end = offs[node + 1];

    float acc[8] = {0, 0, 0, 0, 0, 0, 0, 0};
    for (int i = beg + g; i < end; i += 4) {
        const int2 sw = sorted_sw[i];
        const float w = __int_as_float(sw.y);
        const bf16x8 v = *reinterpret_cast<const bf16x8*>(
            &sup[(size_t)sw.x * D + fl * 8]);
#pragma unroll
        for (int q = 0; q < 8; ++q)
            acc[q] = fmaf(w, bf2f((unsigned short)v[q]), acc[q]);
    }
    // combine the 4 edge-groups (feature ownership identical across groups)
#pragma unroll
    for (int q = 0; q < 8; ++q) {
        acc[q] += __shfl_xor(acc[q], 16);
        acc[q] += __shfl_xor(acc[q], 32);
    }
    if (g == 0) {
        const float4 b0 = *reinterpret_cast<const float4*>(&bias[fl * 8]);
        const float4 b1 = *reinterpret_cast<const float4*>(&bias[fl * 8 + 4]);
        float* o = &out[(size_t)node * D + fl * 8];
        reinterpret_cast<float4*>(o)[0] =
            make_float4(acc[0] + b0.x, acc[1] + b0.y, acc[2] + b0.z, acc[3] + b0.w);
        reinterpret_cast<float4*>(o)[1] =
            make_float4(acc[4] + b1.x, acc[5] + b1.y, acc[6] + b1.z, acc[7] + b1.w);
    }
}

extern "C" void kernel_launch(void* const* d_in, const int* in_sizes, int n_in,
                              void* d_out, int out_size, void* d_ws, size_t ws_size,
                              hipStream_t stream) {
    const float* x      = (const float*)d_in[0];   // [N_NODES, D]
    const float* weight = (const float*)d_in[1];   // [D, D]
    const float* bias   = (const float*)d_in[2];   // [D]
    const int*   eidx   = (const int*)d_in[3];     // [2, N_EDGES] int32
    const float* ew     = (const float*)d_in[4];   // [N_EDGES]
    float* out = (float*)d_out;

    const int* dst_idx = eidx;                     // edge_index[0] (receiver)
    const int* src_idx = eidx + N_EDGES;           // edge_index[1] (neighbor)

    // workspace layout (all sizes multiple of 16 bytes)
    char* p = (char*)d_ws;
    short* sup       = (short*)p;  p += (size_t)N_NODES * D * 2;   // 25,600,000
    int*   counts    = (int*)p;    p += 400000;                    // N_NODES*4
    int*   offs      = (int*)p;    p += 400016;                    // (N_NODES+1)*4 pad
    int*   cursor    = (int*)p;    p += 400000;
    int*   partial   = (int*)p;    p += 416;                       // NCHUNK*4 pad
    short* wt        = (short*)p;  p += (size_t)D * D * 2;         // 32,768
    int2*  sorted_sw = (int2*)p;   p += (size_t)N_EDGES * 8;       // 12,800,000

    // 1) Wt = bf16(W^T); zero counts; support = X @ W via MFMA
    wt_kernel<<<(D * D + 255) / 256, 256, 0, stream>>>(weight, wt);
    hipMemsetAsync(counts, 0, (size_t)N_NODES * 4, stream);
    gemm_mfma_kernel<<<(N_NODES / 16 + 3) / 4, 256, 0, stream>>>(x, wt, sup);

    // 2) counting sort by dst → CSR with (src, ew) payload
    hist_kernel<<<2048, 256, 0, stream>>>(dst_idx, counts);
    scanA_kernel<<<NCHUNK, 256, 0, stream>>>(counts, partial);
    scanB_kernel<<<1, 64, 0, stream>>>(partial);
    scanC_kernel<<<NCHUNK, 256, 0, stream>>>(counts, partial, offs, cursor);
    fill_kernel<<<2048, 256, 0, stream>>>(dst_idx, src_idx, ew, cursor, sorted_sw);

    // 3) aggregate (bias folded in)
    aggregate_kernel<<<(N_NODES + 3) / 4, 256, 0, stream>>>(
        offs, sorted_sw, sup, bias, out);
}

// Round 5
// 185.950 us; speedup vs baseline: 15.5157x; 1.6867x over previous
//
#include <hip/hip_runtime.h>
#include <hip/hip_bf16.h>

#define N_NODES 100000
#define N_EDGES 1600000
#define D 128

#define NBUK 1024
#define BSH 7               // bucket = dst >> 7  (128 nodes per bucket)
#define PA_BLOCKS 200
#define PA_EPB 8000         // edges per bucketing block (200*8000 = 1.6M)

typedef __attribute__((ext_vector_type(8))) short bf16x8;  // 8 bf16 (4 VGPRs)
typedef __attribute__((ext_vector_type(4))) float f32x4;

static __device__ __forceinline__ short f2bf(float f) {
    unsigned u = __builtin_bit_cast(unsigned, f);
    u += 0x7FFFu + ((u >> 16) & 1u);                 // RNE
    return (short)(u >> 16);
}
static __device__ __forceinline__ float bf2f(unsigned short h) {
    unsigned u = ((unsigned)h) << 16;
    return __builtin_bit_cast(float, u);
}

// ---------------------------------------------------------------------------
// Wt[c][k] = bf16(W[k][c])  — 32 KB, built once, L2-resident for the GEMM.
// ---------------------------------------------------------------------------
__global__ void wt_kernel(const float* __restrict__ w, short* __restrict__ wt) {
    const int i = blockIdx.x * blockDim.x + threadIdx.x;
    if (i < D * D) {
        const int k = i / D, c = i % D;
        wt[c * D + k] = f2bf(w[i]);
    }
}

// ---------------------------------------------------------------------------
// support(bf16) = X @ W via MFMA. One wave per 16 rows (6250 waves).
// ---------------------------------------------------------------------------
__global__ __launch_bounds__(256) void gemm_mfma_kernel(
    const float* __restrict__ x, const short* __restrict__ wt,
    short* __restrict__ sup) {
    const int wid = blockIdx.x * 4 + (threadIdx.x >> 6);
    if (wid >= N_NODES / 16) return;
    const int l = threadIdx.x & 63;
    const int r = l & 15, g = l >> 4;
    const size_t row0 = (size_t)wid * 16;

    bf16x8 a[4];
    const float* xp = x + (row0 + r) * D + g * 8;
#pragma unroll
    for (int ks = 0; ks < 4; ++ks) {
        const float4 f0 = *reinterpret_cast<const float4*>(xp + ks * 32);
        const float4 f1 = *reinterpret_cast<const float4*>(xp + ks * 32 + 4);
        bf16x8 t;
        t[0] = f2bf(f0.x); t[1] = f2bf(f0.y); t[2] = f2bf(f0.z); t[3] = f2bf(f0.w);
        t[4] = f2bf(f1.x); t[5] = f2bf(f1.y); t[6] = f2bf(f1.z); t[7] = f2bf(f1.w);
        a[ks] = t;
    }

#pragma unroll
    for (int nt = 0; nt < 8; ++nt) {
        f32x4 acc = {0.f, 0.f, 0.f, 0.f};
        const short* wp = wt + (size_t)(nt * 16 + r) * D + g * 8;
#pragma unroll
        for (int ks = 0; ks < 4; ++ks) {
            const bf16x8 b = *reinterpret_cast<const bf16x8*>(wp + ks * 32);
            acc = __builtin_amdgcn_mfma_f32_16x16x32_bf16(a[ks], b, acc, 0, 0, 0);
        }
        short* sp = sup + (row0 + g * 4) * D + nt * 16 + r;
#pragma unroll
        for (int q = 0; q < 4; ++q) sp[q * D] = f2bf(acc[q]);
    }
}

// ---------------------------------------------------------------------------
// Pass A0: global bucket histogram via per-block LDS histograms.
// ---------------------------------------------------------------------------
__global__ __launch_bounds__(256) void bukhist_kernel(const int* __restrict__ dst,
                                                      int* __restrict__ gcnt) {
    __shared__ int h[NBUK];
    const int t = threadIdx.x;
    for (int j = t; j < NBUK; j += 256) h[j] = 0;
    __syncthreads();
    const int beg = blockIdx.x * PA_EPB;
    const int end = min(beg + PA_EPB, N_EDGES);
    for (int i = beg + t; i < end; i += 256)
        atomicAdd(&h[dst[i] >> BSH], 1);
    __syncthreads();
    for (int j = t; j < NBUK; j += 256)
        if (h[j]) atomicAdd(&gcnt[j], h[j]);
}

// ---------------------------------------------------------------------------
// Exclusive scan of 1024 bucket counts (one block); also writes offs[N_NODES].
// ---------------------------------------------------------------------------
__global__ __launch_bounds__(256) void bukscan_kernel(const int* __restrict__ gcnt,
                                                      int* __restrict__ gbase,
                                                      int* __restrict__ gcur,
                                                      int* __restrict__ offs_last) {
    __shared__ int ts[256];
    const int t = threadIdx.x;
    int loc[4];
    int s = 0;
#pragma unroll
    for (int j = 0; j < 4; ++j) { loc[j] = gcnt[t * 4 + j]; s += loc[j]; }
    ts[t] = s;
    __syncthreads();
    for (int o = 1; o < 256; o <<= 1) {
        const int v = (t >= o) ? ts[t - o] : 0;
        __syncthreads();
        ts[t] += v;
        __syncthreads();
    }
    int excl = ts[t] - s;
#pragma unroll
    for (int j = 0; j < 4; ++j) {
        gbase[t * 4 + j] = excl;
        gcur[t * 4 + j] = excl;
        excl += loc[j];
    }
    if (t == 255) { gbase[NBUK] = excl; *offs_last = excl; }  // = N_EDGES
}

// ---------------------------------------------------------------------------
// Pass A1: scatter edges into bucket regions. One global atomic per nonempty
// (block, bucket) pair reserves a contiguous range; edges of a bucket from
// one block land contiguously (L2-merged writes).
// ---------------------------------------------------------------------------
__global__ __launch_bounds__(256) void bukscatter_kernel(
    const int* __restrict__ dst, const int* __restrict__ src,
    const float* __restrict__ ew, int* __restrict__ gcur,
    int* __restrict__ inter_dst, int2* __restrict__ inter_sw) {
    __shared__ int h[NBUK];
    const int t = threadIdx.x;
    for (int j = t; j < NBUK; j += 256) h[j] = 0;
    __syncthreads();
    const int beg = blockIdx.x * PA_EPB;
    const int end = min(beg + PA_EPB, N_EDGES);
    for (int i = beg + t; i < end; i += 256)
        atomicAdd(&h[dst[i] >> BSH], 1);
    __syncthreads();
    for (int j = t; j < NBUK; j += 256) {
        const int c = h[j];
        h[j] = c ? atomicAdd(&gcur[j], c) : 0;   // h becomes the block's cursor
    }
    __syncthreads();
    for (int i = beg + t; i < end; i += 256) {
        const int d = dst[i];
        const int pos = atomicAdd(&h[d >> BSH], 1);
        inter_dst[pos] = d;
        inter_sw[pos] = make_int2(src[i], __float_as_int(ew[i]));
    }
}

// ---------------------------------------------------------------------------
// Pass B: one block per bucket (~1600 edges over 128 node ids). LDS counting
// sort: writes offs[] for its 128 nodes and scatters payloads into the
// bucket's contiguous output window (16 KB, L2-resident).
// ---------------------------------------------------------------------------
__global__ __launch_bounds__(256) void buksort_kernel(
    const int* __restrict__ gbase, const int* __restrict__ inter_dst,
    const int2* __restrict__ inter_sw, int* __restrict__ offs,
    int2* __restrict__ sorted_sw) {
    __shared__ int h[128];
    __shared__ int cur[128];
    const int b = blockIdx.x, t = threadIdx.x;
    const int beg = gbase[b], end = gbase[b + 1];
    if (t < 128) h[t] = 0;
    __syncthreads();
    for (int i = beg + t; i < end; i += 256)
        atomicAdd(&h[inter_dst[i] & 127], 1);
    __syncthreads();
    if (t < 128) cur[t] = h[t];
    __syncthreads();
    for (int o = 1; o < 128; o <<= 1) {         // inclusive scan over 128 bins
        int v = 0;
        if (t < 128 && t >= o) v = cur[t - o];
        __syncthreads();
        if (t < 128) cur[t] += v;
        __syncthreads();
    }
    if (t < 128) {
        const int node = (b << BSH) + t;
        const int off = beg + cur[t] - h[t];    // exclusive position
        if (node < N_NODES) offs[node] = off;
        cur[t] = off;
    }
    __syncthreads();
    for (int i = beg + t; i < end; i += 256) {
        const int d = inter_dst[i];
        const int pos = atomicAdd(&cur[d & 127], 1);
        sorted_sw[pos] = inter_sw[i];
    }
}

// ---------------------------------------------------------------------------
// Aggregate: one wave per node; 4 edge-groups x 16 lanes; lane loads bf16x8
// (16 B) of the gathered row -> 4 independent row-gathers in flight.
// ---------------------------------------------------------------------------
__global__ __launch_bounds__(256) void aggregate_kernel(
    const int* __restrict__ offs, const int2* __restrict__ sorted_sw,
    const short* __restrict__ sup, const float* __restrict__ bias,
    float* __restrict__ out) {
    const int node = blockIdx.x * 4 + (threadIdx.x >> 6);
    if (node >= N_NODES) return;
    const int lane = threadIdx.x & 63;
    const int g = lane >> 4;            // edge group 0..3
    const int fl = lane & 15;           // feature lane: features fl*8 .. fl*8+7

    const int beg = offs[node];
    const int end = offs[node + 1];

    float acc[8] = {0, 0, 0, 0, 0, 0, 0, 0};
    for (int i = beg + g; i < end; i += 4) {
        const int2 sw = sorted_sw[i];
        const float w = __int_as_float(sw.y);
        const bf16x8 v = *reinterpret_cast<const bf16x8*>(
            &sup[(size_t)sw.x * D + fl * 8]);
#pragma unroll
        for (int q = 0; q < 8; ++q)
            acc[q] = fmaf(w, bf2f((unsigned short)v[q]), acc[q]);
    }
#pragma unroll
    for (int q = 0; q < 8; ++q) {
        acc[q] += __shfl_xor(acc[q], 16);
        acc[q] += __shfl_xor(acc[q], 32);
    }
    if (g == 0) {
        const float4 b0 = *reinterpret_cast<const float4*>(&bias[fl * 8]);
        const float4 b1 = *reinterpret_cast<const float4*>(&bias[fl * 8 + 4]);
        float* o = &out[(size_t)node * D + fl * 8];
        reinterpret_cast<float4*>(o)[0] =
            make_float4(acc[0] + b0.x, acc[1] + b0.y, acc[2] + b0.z, acc[3] + b0.w);
        reinterpret_cast<float4*>(o)[1] =
            make_float4(acc[4] + b1.x, acc[5] + b1.y, acc[6] + b1.z, acc[7] + b1.w);
    }
}

extern "C" void kernel_launch(void* const* d_in, const int* in_sizes, int n_in,
                              void* d_out, int out_size, void* d_ws, size_t ws_size,
                              hipStream_t stream) {
    const float* x      = (const float*)d_in[0];   // [N_NODES, D]
    const float* weight = (const float*)d_in[1];   // [D, D]
    const float* bias   = (const float*)d_in[2];   // [D]
    const int*   eidx   = (const int*)d_in[3];     // [2, N_EDGES] int32
    const float* ew     = (const float*)d_in[4];   // [N_EDGES]
    float* out = (float*)d_out;

    const int* dst_idx = eidx;                     // edge_index[0] (receiver)
    const int* src_idx = eidx + N_EDGES;           // edge_index[1] (neighbor)

    // workspace layout (16B-aligned chunks), total ~58.0 MB
    char* p = (char*)d_ws;
    short* sup       = (short*)p;  p += (size_t)N_NODES * D * 2;   // 25,600,000
    short* wt        = (short*)p;  p += (size_t)D * D * 2;         // 32,768
    int*   gcnt      = (int*)p;    p += NBUK * 4;                  // 4,096
    int*   gbase     = (int*)p;    p += (NBUK + 1) * 4 + 12;       // 4,112
    int*   gcur      = (int*)p;    p += NBUK * 4;                  // 4,096
    int*   offs      = (int*)p;    p += (size_t)(N_NODES + 1) * 4 + 12; // 400,016
    int*   inter_dst = (int*)p;    p += (size_t)N_EDGES * 4;       // 6,400,000
    int2*  inter_sw  = (int2*)p;   p += (size_t)N_EDGES * 8;       // 12,800,000
    int2*  sorted_sw = (int2*)p;   p += (size_t)N_EDGES * 8;       // 12,800,000

    // 1) Wt = bf16(W^T); support = X @ W via MFMA
    wt_kernel<<<(D * D + 255) / 256, 256, 0, stream>>>(weight, wt);
    hipMemsetAsync(gcnt, 0, (size_t)NBUK * 4, stream);
    gemm_mfma_kernel<<<(N_NODES / 16 + 3) / 4, 256, 0, stream>>>(x, wt, sup);

    // 2) two-level bucket sort by dst → CSR (offs) + dst-sorted (src,ew)
    bukhist_kernel<<<PA_BLOCKS, 256, 0, stream>>>(dst_idx, gcnt);
    bukscan_kernel<<<1, 256, 0, stream>>>(gcnt, gbase, gcur, &offs[N_NODES]);
    bukscatter_kernel<<<PA_BLOCKS, 256, 0, stream>>>(dst_idx, src_idx, ew, gcur,
                                                     inter_dst, inter_sw);
    buksort_kernel<<<NBUK, 256, 0, stream>>>(gbase, inter_dst, inter_sw, offs,
                                             sorted_sw);

    // 3) aggregate (bias folded in)
    aggregate_kernel<<<(N_NODES + 3) / 4, 256, 0, stream>>>(
        offs, sorted_sw, sup, bias, out);
}

// Round 6
// 159.635 us; speedup vs baseline: 18.0734x; 1.1648x over previous
//
#include <hip/hip_runtime.h>
#include <hip/hip_bf16.h>

#define N_NODES 100000
#define N_EDGES 1600000
#define D 128

#define NBUK 1024
#define BSH 7               // bucket = dst >> 7  (128 nodes per bucket)
#define PA_BLOCKS 256
#define PA_EPB 6250         // 256 * 6250 = 1.6M edges
#define SRC_MASK 0x01FFFFFF // low 25 bits carry src (< 2^17); bits 25.. carry dst&127

typedef __attribute__((ext_vector_type(8))) short bf16x8;  // 8 bf16 (4 VGPRs)
typedef __attribute__((ext_vector_type(4))) float f32x4;

static __device__ __forceinline__ short f2bf(float f) {
    unsigned u = __builtin_bit_cast(unsigned, f);
    u += 0x7FFFu + ((u >> 16) & 1u);                 // RNE
    return (short)(u >> 16);
}
static __device__ __forceinline__ float bf2f(unsigned short h) {
    unsigned u = ((unsigned)h) << 16;
    return __builtin_bit_cast(float, u);
}

// ---------------------------------------------------------------------------
// Wt[c][k] = bf16(W[k][c])  — 32 KB, built once, L2-resident for the GEMM.
// ---------------------------------------------------------------------------
__global__ void wt_kernel(const float* __restrict__ w, short* __restrict__ wt) {
    const int i = blockIdx.x * blockDim.x + threadIdx.x;
    if (i < D * D) {
        const int k = i / D, c = i % D;
        wt[c * D + k] = f2bf(w[i]);
    }
}

// ---------------------------------------------------------------------------
// support(bf16) = X @ W via MFMA. One wave per 16 rows (6250 waves).
// ---------------------------------------------------------------------------
__global__ __launch_bounds__(256) void gemm_mfma_kernel(
    const float* __restrict__ x, const short* __restrict__ wt,
    short* __restrict__ sup) {
    const int wid = blockIdx.x * 4 + (threadIdx.x >> 6);
    if (wid >= N_NODES / 16) return;
    const int l = threadIdx.x & 63;
    const int r = l & 15, g = l >> 4;
    const size_t row0 = (size_t)wid * 16;

    bf16x8 a[4];
    const float* xp = x + (row0 + r) * D + g * 8;
#pragma unroll
    for (int ks = 0; ks < 4; ++ks) {
        const float4 f0 = *reinterpret_cast<const float4*>(xp + ks * 32);
        const float4 f1 = *reinterpret_cast<const float4*>(xp + ks * 32 + 4);
        bf16x8 t;
        t[0] = f2bf(f0.x); t[1] = f2bf(f0.y); t[2] = f2bf(f0.z); t[3] = f2bf(f0.w);
        t[4] = f2bf(f1.x); t[5] = f2bf(f1.y); t[6] = f2bf(f1.z); t[7] = f2bf(f1.w);
        a[ks] = t;
    }

#pragma unroll
    for (int nt = 0; nt < 8; ++nt) {
        f32x4 acc = {0.f, 0.f, 0.f, 0.f};
        const short* wp = wt + (size_t)(nt * 16 + r) * D + g * 8;
#pragma unroll
        for (int ks = 0; ks < 4; ++ks) {
            const bf16x8 b = *reinterpret_cast<const bf16x8*>(wp + ks * 32);
            acc = __builtin_amdgcn_mfma_f32_16x16x32_bf16(a[ks], b, acc, 0, 0, 0);
        }
        short* sp = sup + (row0 + g * 4) * D + nt * 16 + r;
#pragma unroll
        for (int q = 0; q < 4; ++q) sp[q * D] = f2bf(acc[q]);
    }
}

// ---------------------------------------------------------------------------
// Pass A0: global bucket histogram via per-block LDS histograms.
// 1024 threads/block for latency hiding (16 waves/CU).
// ---------------------------------------------------------------------------
__global__ __launch_bounds__(1024) void bukhist_kernel(const int* __restrict__ dst,
                                                       int* __restrict__ gcnt) {
    __shared__ int h[NBUK];
    const int t = threadIdx.x;
    if (t < NBUK) h[t] = 0;
    __syncthreads();
    const int beg = blockIdx.x * PA_EPB;
    const int end = min(beg + PA_EPB, N_EDGES);
    for (int i = beg + t; i < end; i += 1024)
        atomicAdd(&h[dst[i] >> BSH], 1);
    __syncthreads();
    if (t < NBUK && h[t]) atomicAdd(&gcnt[t], h[t]);
}

// ---------------------------------------------------------------------------
// Exclusive scan of 1024 bucket counts (one block); also writes offs[N_NODES].
// ---------------------------------------------------------------------------
__global__ __launch_bounds__(256) void bukscan_kernel(const int* __restrict__ gcnt,
                                                      int* __restrict__ gbase,
                                                      int* __restrict__ gcur,
                                                      int* __restrict__ offs_last) {
    __shared__ int ts[256];
    const int t = threadIdx.x;
    int loc[4];
    int s = 0;
#pragma unroll
    for (int j = 0; j < 4; ++j) { loc[j] = gcnt[t * 4 + j]; s += loc[j]; }
    ts[t] = s;
    __syncthreads();
    for (int o = 1; o < 256; o <<= 1) {
        const int v = (t >= o) ? ts[t - o] : 0;
        __syncthreads();
        ts[t] += v;
        __syncthreads();
    }
    int excl = ts[t] - s;
#pragma unroll
    for (int j = 0; j < 4; ++j) {
        gbase[t * 4 + j] = excl;
        gcur[t * 4 + j] = excl;
        excl += loc[j];
    }
    if (t == 255) { gbase[NBUK] = excl; *offs_last = excl; }  // = N_EDGES
}

// ---------------------------------------------------------------------------
// Pass A1: scatter packed (src|d7, ew) into bucket regions. One global atomic
// per nonempty (block, bucket) reserves a contiguous range; runs of ~6 edges
// land contiguously. 1024 threads/block.
// ---------------------------------------------------------------------------
__global__ __launch_bounds__(1024) void bukscatter_kernel(
    const int* __restrict__ dst, const int* __restrict__ src,
    const float* __restrict__ ew, int* __restrict__ gcur,
    int2* __restrict__ inter_sw) {
    __shared__ int h[NBUK];
    const int t = threadIdx.x;
    if (t < NBUK) h[t] = 0;
    __syncthreads();
    const int beg = blockIdx.x * PA_EPB;
    const int end = min(beg + PA_EPB, N_EDGES);
    for (int i = beg + t; i < end; i += 1024)
        atomicAdd(&h[dst[i] >> BSH], 1);
    __syncthreads();
    if (t < NBUK) {
        const int c = h[t];
        h[t] = c ? atomicAdd(&gcur[t], c) : 0;   // h becomes the block's cursor
    }
    __syncthreads();
    for (int i = beg + t; i < end; i += 1024) {
        const int d = dst[i];
        const int pos = atomicAdd(&h[d >> BSH], 1);
        inter_sw[pos] = make_int2(src[i] | ((d & 127) << 25), __float_as_int(ew[i]));
    }
}

// ---------------------------------------------------------------------------
// Pass B: one block per bucket (~1600 edges over 128 node ids). LDS counting
// sort: writes offs[] for its 128 nodes and scatters payloads into the
// bucket's contiguous output window (12.5 KB avg, L2-resident).
// ---------------------------------------------------------------------------
__global__ __launch_bounds__(512) void buksort_kernel(
    const int* __restrict__ gbase, const int2* __restrict__ inter_sw,
    int* __restrict__ offs, int2* __restrict__ sorted_sw) {
    __shared__ int h[128];
    __shared__ int cur[128];
    const int b = blockIdx.x, t = threadIdx.x;
    const int beg = gbase[b], end = gbase[b + 1];
    if (t < 128) h[t] = 0;
    __syncthreads();
    for (int i = beg + t; i < end; i += 512)
        atomicAdd(&h[(unsigned)inter_sw[i].x >> 25], 1);
    __syncthreads();
    if (t < 128) cur[t] = h[t];
    __syncthreads();
    for (int o = 1; o < 128; o <<= 1) {         // inclusive scan over 128 bins
        int v = 0;
        if (t < 128 && t >= o) v = cur[t - o];
        __syncthreads();
        if (t < 128) cur[t] += v;
        __syncthreads();
    }
    if (t < 128) {
        const int node = (b << BSH) + t;
        const int off = beg + cur[t] - h[t];    // exclusive position
        if (node < N_NODES) offs[node] = off;
        cur[t] = off;
    }
    __syncthreads();
    for (int i = beg + t; i < end; i += 512) {
        const int2 sw = inter_sw[i];
        const int pos = atomicAdd(&cur[(unsigned)sw.x >> 25], 1);
        sorted_sw[pos] = make_int2(sw.x & SRC_MASK, sw.y);
    }
}

// ---------------------------------------------------------------------------
// Aggregate: one wave per node; 4 edge-groups x 16 lanes; lane loads bf16x8
// (16 B) of the gathered row -> 4 independent row-gathers in flight.
// ---------------------------------------------------------------------------
__global__ __launch_bounds__(256) void aggregate_kernel(
    const int* __restrict__ offs, const int2* __restrict__ sorted_sw,
    const short* __restrict__ sup, const float* __restrict__ bias,
    float* __restrict__ out) {
    const int node = blockIdx.x * 4 + (threadIdx.x >> 6);
    if (node >= N_NODES) return;
    const int lane = threadIdx.x & 63;
    const int g = lane >> 4;            // edge group 0..3
    const int fl = lane & 15;           // feature lane: features fl*8 .. fl*8+7

    const int beg = offs[node];
    const int end = offs[node + 1];

    float acc[8] = {0, 0, 0, 0, 0, 0, 0, 0};
    for (int i = beg + g; i < end; i += 4) {
        const int2 sw = sorted_sw[i];
        const float w = __int_as_float(sw.y);
        const bf16x8 v = *reinterpret_cast<const bf16x8*>(
            &sup[(size_t)sw.x * D + fl * 8]);
#pragma unroll
        for (int q = 0; q < 8; ++q)
            acc[q] = fmaf(w, bf2f((unsigned short)v[q]), acc[q]);
    }
#pragma unroll
    for (int q = 0; q < 8; ++q) {
        acc[q] += __shfl_xor(acc[q], 16);
        acc[q] += __shfl_xor(acc[q], 32);
    }
    if (g == 0) {
        const float4 b0 = *reinterpret_cast<const float4*>(&bias[fl * 8]);
        const float4 b1 = *reinterpret_cast<const float4*>(&bias[fl * 8 + 4]);
        float* o = &out[(size_t)node * D + fl * 8];
        reinterpret_cast<float4*>(o)[0] =
            make_float4(acc[0] + b0.x, acc[1] + b0.y, acc[2] + b0.z, acc[3] + b0.w);
        reinterpret_cast<float4*>(o)[1] =
            make_float4(acc[4] + b1.x, acc[5] + b1.y, acc[6] + b1.z, acc[7] + b1.w);
    }
}

extern "C" void kernel_launch(void* const* d_in, const int* in_sizes, int n_in,
                              void* d_out, int out_size, void* d_ws, size_t ws_size,
                              hipStream_t stream) {
    const float* x      = (const float*)d_in[0];   // [N_NODES, D]
    const float* weight = (const float*)d_in[1];   // [D, D]
    const float* bias   = (const float*)d_in[2];   // [D]
    const int*   eidx   = (const int*)d_in[3];     // [2, N_EDGES] int32
    const float* ew     = (const float*)d_in[4];   // [N_EDGES]
    float* out = (float*)d_out;

    const int* dst_idx = eidx;                     // edge_index[0] (receiver)
    const int* src_idx = eidx + N_EDGES;           // edge_index[1] (neighbor)

    // workspace layout (16B-aligned chunks), total ~52 MB
    char* p = (char*)d_ws;
    short* sup       = (short*)p;  p += (size_t)N_NODES * D * 2;   // 25,600,000
    short* wt        = (short*)p;  p += (size_t)D * D * 2;         // 32,768
    int*   gcnt      = (int*)p;    p += NBUK * 4;                  // 4,096
    int*   gbase     = (int*)p;    p += (NBUK + 1) * 4 + 12;       // 4,112
    int*   gcur      = (int*)p;    p += NBUK * 4;                  // 4,096
    int*   offs      = (int*)p;    p += (size_t)(N_NODES + 1) * 4 + 12; // 400,016
    int2*  inter_sw  = (int2*)p;   p += (size_t)N_EDGES * 8;       // 12,800,000
    int2*  sorted_sw = (int2*)p;   p += (size_t)N_EDGES * 8;       // 12,800,000

    // 1) Wt = bf16(W^T); support = X @ W via MFMA
    wt_kernel<<<(D * D + 255) / 256, 256, 0, stream>>>(weight, wt);
    hipMemsetAsync(gcnt, 0, (size_t)NBUK * 4, stream);
    gemm_mfma_kernel<<<(N_NODES / 16 + 3) / 4, 256, 0, stream>>>(x, wt, sup);

    // 2) two-level bucket sort by dst → CSR (offs) + dst-sorted (src,ew)
    bukhist_kernel<<<PA_BLOCKS, 1024, 0, stream>>>(dst_idx, gcnt);
    bukscan_kernel<<<1, 256, 0, stream>>>(gcnt, gbase, gcur, &offs[N_NODES]);
    bukscatter_kernel<<<PA_BLOCKS, 1024, 0, stream>>>(dst_idx, src_idx, ew, gcur,
                                                      inter_sw);
    buksort_kernel<<<NBUK, 512, 0, stream>>>(gbase, inter_sw, offs, sorted_sw);

    // 3) aggregate (bias folded in)
    aggregate_kernel<<<(N_NODES + 3) / 4, 256, 0, stream>>>(
        offs, sorted_sw, sup, bias, out);
}